// Round 5
// baseline (19099.113 us; speedup 1.0000x reference)
//
#include <hip/hip_runtime.h>
#include <hip/hip_bf16.h>

#define EMBED   1024
#define HIDDEN  2048
#define G4      8192   // 4*HIDDEN
#define LENGTH  4096

typedef unsigned int   u32;
typedef unsigned short u16;
typedef __attribute__((ext_vector_type(4))) float f32x4;
typedef __attribute__((ext_vector_type(8))) short short8;

__device__ __forceinline__ u16 f2bf(float x){
  __hip_bfloat16 h = __float2bfloat16(x);   // RNE
  return __builtin_bit_cast(u16, h);
}
__device__ __forceinline__ float bf2f(u16 b){
  return __uint_as_float(((u32)b) << 16);
}

#if __has_builtin(__builtin_amdgcn_fdot2_f32_bf16)
typedef __attribute__((ext_vector_type(2))) __bf16 bf16x2;
__device__ __forceinline__ float dot2acc(u32 a, u32 b, float c){
  return __builtin_amdgcn_fdot2_f32_bf16(__builtin_bit_cast(bf16x2, a),
                                         __builtin_bit_cast(bf16x2, b), c, false);
}
#else
__device__ __forceinline__ float dot2acc(u32 a, u32 b, float c){
  float r = c;
  r += __uint_as_float(a << 16)          * __uint_as_float(b << 16);
  r += __uint_as_float(a & 0xffff0000u)  * __uint_as_float(b & 0xffff0000u);
  return r;
}
#endif

__device__ __forceinline__ float fsig(float x){ return 1.f/(1.f + __expf(-x)); }
__device__ __forceinline__ float ftanh_(float x){ return 1.f - 2.f/(1.f + __expf(2.f*x)); }

// ---------------- fp32 -> bf16 conversion (vectorized) ----------------
__global__ void conv_bf16(const float* __restrict__ src, u16* __restrict__ dst, int n4){
  int i = blockIdx.x * blockDim.x + threadIdx.x;
  if (i < n4){
    float4 v = reinterpret_cast<const float4*>(src)[i];
    ushort4 o;
    o.x = f2bf(v.x); o.y = f2bf(v.y); o.z = f2bf(v.z); o.w = f2bf(v.w);
    reinterpret_cast<ushort4*>(dst)[i] = o;
  }
}

// ---------------- x_proj GEMM: out[m][j][g] = sum_k A[m][k]*B[g*2048+j][k] + bias ----------------
__global__ __launch_bounds__(256) void gemm_xproj(
    const u16* __restrict__ A, const u16* __restrict__ B,
    const float* __restrict__ b_ih, const float* __restrict__ b_hh,
    u16* __restrict__ C)
{
  __shared__ __align__(16) u16 As[64][40];
  __shared__ __align__(16) u16 Bs[64][40];
  const int tid  = threadIdx.x;
  const int lane = tid & 63, wid = tid >> 6;
  const int wr = wid >> 1, wc = wid & 1;
  const int m0 = blockIdx.y * 64, n0 = blockIdx.x * 64;
  const int srow = tid >> 2, sseg = (tid & 3) * 8;

  f32x4 acc[2][2] = {};
  for (int k0 = 0; k0 < EMBED; k0 += 32){
    *(short8*)&As[srow][sseg] = *(const short8*)&A[(size_t)(m0 + srow) * EMBED + k0 + sseg];
    *(short8*)&Bs[srow][sseg] = *(const short8*)&B[(size_t)(n0 + srow) * EMBED + k0 + sseg];
    __syncthreads();
    const int rr = lane & 15, kg = (lane >> 4) * 8;
    #pragma unroll
    for (int mi = 0; mi < 2; ++mi){
      short8 a = *(const short8*)&As[wr*32 + mi*16 + rr][kg];
      #pragma unroll
      for (int ni = 0; ni < 2; ++ni){
        short8 b = *(const short8*)&Bs[wc*32 + ni*16 + rr][kg];
        acc[mi][ni] = __builtin_amdgcn_mfma_f32_16x16x32_bf16(a, b, acc[mi][ni], 0, 0, 0);
      }
    }
    __syncthreads();
  }
  const int rr = lane & 15, rg = (lane >> 4) * 4;
  #pragma unroll
  for (int ni = 0; ni < 2; ++ni){
    int n = n0 + wc*32 + ni*16 + rr;      // n = gate*2048 + j
    int g = n >> 11, j = n & 2047;
    float bias = b_ih[n] + b_hh[n];
    #pragma unroll
    for (int mi = 0; mi < 2; ++mi){
      #pragma unroll
      for (int r = 0; r < 4; ++r){
        int m = m0 + wr*32 + mi*16 + rg + r;
        C[(size_t)m * G4 + j*4 + g] = f2bf(acc[mi][ni][r] + bias);
      }
    }
  }
}

// ---------------- persistent LSTM scan (LDS-resident weights) ----------------
// 256 WGs x 512 threads, 1 WG/CU (forced by 132 KB dynamic LDS). Wave w of WG
// wg owns hidden unit j = wg*8 + w: gate rows {g*2048+j}. The WG's W_hh slice
// (32 rows x 2048 cols) is staged ONCE into LDS as packed bf16 pairs (128 KB);
// per step each wave re-reads its 4 rows from LDS (conflict-free 16B/lane
// pattern, same as the h reads that measured 0 conflicts in rounds 2-4).
// Rounds 2-4 showed the register allocator refuses >64 live VGPRs (occupancy
// heuristic) -> register-resident weights spill to scratch; LDS is the
// guaranteed-mechanism alternative. __syncthreads clobbers LDS each step so
// weight loads cannot be hoisted out of the loop into spills.
// LDS map (u32 units): wlds[(g*8+w)*1024 + idx], idx = colpair; h_bf (u16) at
// smem+32768: h_bf[r][i] = h[r*512+i], r=0..3.
// h broadcast: htag[2][2048] words (tag<<16 | bf16(h)), relaxed agent-scope
// atomics, double-buffered by step parity; tag+data in one word -> no fences.
__global__ __launch_bounds__(512) void lstm_scan(
    const float* __restrict__ Whh,   // [8192][2048] fp32
    const u16*  __restrict__ xp,     // [4096][2048][4] bf16 (packed by gemm)
    u32* htag)                       // [2][2048]
{
  extern __shared__ __align__(16) u32 smem[];      // 32768 u32 wlds + 1024 u32 h_bf
  u32* wlds = smem;
  u16* h_bf = (u16*)(smem + 32768);                // [4][512]

  const int wg = blockIdx.x;
  const int tid = threadIdx.x;
  const int w = tid >> 6, lane = tid & 63;
  const int jrow = wg*8 + w;

  // ---- one-time weight staging: fp32 global -> packed bf16 pairs in LDS ----
  #pragma unroll
  for (int g = 0; g < 4; ++g){
    const float* row = Whh + (size_t)(g*HIDDEN + jrow) * HIDDEN;
    u32* dst = wlds + (g*8 + w) * 1024;
    #pragma unroll
    for (int r = 0; r < 4; ++r){
      const float* s = row + r*512 + lane*8;
      float4 a = *(const float4*)(s);
      float4 b = *(const float4*)(s + 4);
      uint4 pk;
      pk.x = (u32)f2bf(a.x) | ((u32)f2bf(a.y) << 16);
      pk.y = (u32)f2bf(a.z) | ((u32)f2bf(a.w) << 16);
      pk.z = (u32)f2bf(b.x) | ((u32)f2bf(b.y) << 16);
      pk.w = (u32)f2bf(b.z) | ((u32)f2bf(b.w) << 16);
      *(uint4*)(dst + r*256 + lane*4) = pk;
    }
  }
  __syncthreads();

  float c_reg = 0.f;
  // software-pipelined x_proj prefetch: one 8B load per wave per step
  ushort4 xv_cur = {0,0,0,0}, xv_nxt = {0,0,0,0};
  if (lane == 0) xv_cur = *(const ushort4*)(xp + (size_t)0 * G4 + jrow * 4);

  const u32* w0 = wlds + (0*8 + w) * 1024 + lane*4;
  const u32* w1 = wlds + (1*8 + w) * 1024 + lane*4;
  const u32* w2 = wlds + (2*8 + w) * 1024 + lane*4;
  const u32* w3 = wlds + (3*8 + w) * 1024 + lane*4;

  for (int t = 0; t < LENGTH; ++t){
    if (lane == 0 && t + 1 < LENGTH)
      xv_nxt = *(const ushort4*)(xp + (size_t)(t + 1) * G4 + jrow * 4);

    // acquire step-t h (tag == t), buffer t&1; coalesced poll
    u32* src = htag + ((t & 1) << 11);
    const u32 want = (u32)t;
    u32 v0, v1, v2, v3;
    for (;;){
      v0 = __hip_atomic_load(&src[tid       ], __ATOMIC_RELAXED, __HIP_MEMORY_SCOPE_AGENT);
      v1 = __hip_atomic_load(&src[tid +  512], __ATOMIC_RELAXED, __HIP_MEMORY_SCOPE_AGENT);
      v2 = __hip_atomic_load(&src[tid + 1024], __ATOMIC_RELAXED, __HIP_MEMORY_SCOPE_AGENT);
      v3 = __hip_atomic_load(&src[tid + 1536], __ATOMIC_RELAXED, __HIP_MEMORY_SCOPE_AGENT);
      if ((v0 >> 16) == want && (v1 >> 16) == want &&
          (v2 >> 16) == want && (v3 >> 16) == want) break;
      __builtin_amdgcn_s_sleep(1);
    }
    h_bf[0*512 + tid] = (u16)v0;
    h_bf[1*512 + tid] = (u16)v1;
    h_bf[2*512 + tid] = (u16)v2;
    h_bf[3*512 + tid] = (u16)v3;
    __syncthreads();

    // h fragments: chunk r covers h[r*512 + lane*8 .. +7] (conflict-free b128)
    uint4 ha = *(const uint4*)&h_bf[0*512 + lane*8];
    uint4 hb = *(const uint4*)&h_bf[1*512 + lane*8];
    uint4 hc = *(const uint4*)&h_bf[2*512 + lane*8];
    uint4 hd = *(const uint4*)&h_bf[3*512 + lane*8];

    float a0 = 0.f, a1 = 0.f, a2 = 0.f, a3 = 0.f;
    #define GATE_DOT(acc, wp) { \
      uint4 qa = *(const uint4*)(wp);       \
      uint4 qb = *(const uint4*)(wp + 256); \
      uint4 qc = *(const uint4*)(wp + 512); \
      uint4 qd = *(const uint4*)(wp + 768); \
      acc = dot2acc(qa.x, ha.x, acc); acc = dot2acc(qa.y, ha.y, acc); \
      acc = dot2acc(qa.z, ha.z, acc); acc = dot2acc(qa.w, ha.w, acc); \
      acc = dot2acc(qb.x, hb.x, acc); acc = dot2acc(qb.y, hb.y, acc); \
      acc = dot2acc(qb.z, hb.z, acc); acc = dot2acc(qb.w, hb.w, acc); \
      acc = dot2acc(qc.x, hc.x, acc); acc = dot2acc(qc.y, hc.y, acc); \
      acc = dot2acc(qc.z, hc.z, acc); acc = dot2acc(qc.w, hc.w, acc); \
      acc = dot2acc(qd.x, hd.x, acc); acc = dot2acc(qd.y, hd.y, acc); \
      acc = dot2acc(qd.z, hd.z, acc); acc = dot2acc(qd.w, hd.w, acc); }
    GATE_DOT(a0, w0); GATE_DOT(a1, w1); GATE_DOT(a2, w2); GATE_DOT(a3, w3);
    #undef GATE_DOT

    #pragma unroll
    for (int m = 32; m >= 1; m >>= 1){
      a0 += __shfl_xor(a0, m, 64);
      a1 += __shfl_xor(a1, m, 64);
      a2 += __shfl_xor(a2, m, 64);
      a3 += __shfl_xor(a3, m, 64);
    }
    if (lane == 0){
      float gi = fsig (a0 + bf2f(xv_cur.x));
      float gf = fsig (a1 + bf2f(xv_cur.y));
      float gg = ftanh_(a2 + bf2f(xv_cur.z));
      float go = fsig (a3 + bf2f(xv_cur.w));
      c_reg = gf * c_reg + gi * gg;
      float h = go * ftanh_(c_reg);
      u32 word = ((u32)(t + 1) << 16) | (u32)f2bf(h);
      __hip_atomic_store(&htag[(((t + 1) & 1) << 11) + jrow], word,
                         __ATOMIC_RELAXED, __HIP_MEMORY_SCOPE_AGENT);
    }
    xv_cur = xv_nxt;
    // single barrier per step: poll success for t+1 implies every wave of every
    // WG published t+1, which happens only after that wave finished reading
    // step-t h_bf -> next step's h_bf writes can't race this step's reads.
  }
}

// ---------------- final head: sigmoid(h . W_fc + b_fc) ----------------
__global__ __launch_bounds__(256) void head_k(const u32* __restrict__ htag,
                                              const float* __restrict__ Wfc,
                                              const float* __restrict__ bfc,
                                              float* __restrict__ out){
  __shared__ float red[256];
  int tid = threadIdx.x;
  float s = 0.f;
  #pragma unroll
  for (int k = 0; k < 8; ++k){
    int j = tid * 8 + k;
    s += bf2f((u16)(htag[j] & 0xffffu)) * Wfc[j];   // tag 4096 lives in buffer 0
  }
  red[tid] = s;
  __syncthreads();
  for (int k = 128; k > 0; k >>= 1){
    if (tid < k) red[tid] += red[tid + k];
    __syncthreads();
  }
  if (tid == 0) out[0] = 1.f / (1.f + __expf(-(red[0] + bfc[0])));
}

// ---------------- launch ----------------
extern "C" void kernel_launch(void* const* d_in, const int* in_sizes, int n_in,
                              void* d_out, int out_size, void* d_ws, size_t ws_size,
                              hipStream_t stream){
  const float* x   = (const float*)d_in[0];   // [1,4096,1024]
  const float* Wih = (const float*)d_in[1];   // [8192,1024]
  const float* Whh = (const float*)d_in[2];   // [8192,2048]
  const float* bih = (const float*)d_in[3];   // [8192]
  const float* bhh = (const float*)d_in[4];   // [8192]
  const float* Wfc = (const float*)d_in[5];   // [1,2048]
  const float* bfc = (const float*)d_in[6];   // [1]
  float* out = (float*)d_out;

  char* ws = (char*)d_ws;
  u16* xp     = (u16*)(ws);                    // 4096*8192*2 = 67108864
  u16* x_bf   = (u16*)(ws + 67108864);         // 8388608
  u16* wih_bf = (u16*)(ws + 75497472);         // 16777216
  u32* htag   = (u32*)(ws + 92274688);         // 2*2048*4 = 16384

  hipMemsetAsync(htag, 0, 2 * HIDDEN * sizeof(u32), stream);
  conv_bf16<<<(EMBED*LENGTH/4 + 255)/256, 256, 0, stream>>>(x, x_bf, EMBED*LENGTH/4);
  conv_bf16<<<(G4*EMBED/4 + 255)/256, 256, 0, stream>>>(Wih, wih_bf, G4*EMBED/4);
  dim3 gg(G4/64, LENGTH/64);
  gemm_xproj<<<gg, 256, 0, stream>>>(x_bf, wih_bf, bih, bhh, xp);
  size_t lds_bytes = 32768 * 4 + 4096;         // 128KB weights + 4KB h_bf
  lstm_scan<<<256, 512, lds_bytes, stream>>>(Whh, xp, htag);
  head_k<<<1, 256, 0, stream>>>(htag, Wfc, bfc, out);
}

// Round 6
// 12638.430 us; speedup vs baseline: 1.5112x; 1.5112x over previous
//
#include <hip/hip_runtime.h>
#include <hip/hip_bf16.h>

#define EMBED   1024
#define HIDDEN  2048
#define G4      8192   // 4*HIDDEN
#define LENGTH  4096

typedef unsigned int   u32;
typedef unsigned short u16;
typedef __attribute__((ext_vector_type(4))) float f32x4;
typedef __attribute__((ext_vector_type(8))) short short8;

__device__ __forceinline__ u16 f2bf(float x){
  __hip_bfloat16 h = __float2bfloat16(x);   // RNE
  return __builtin_bit_cast(u16, h);
}
__device__ __forceinline__ float bf2f(u16 b){
  return __uint_as_float(((u32)b) << 16);
}

#if __has_builtin(__builtin_amdgcn_fdot2_f32_bf16)
typedef __attribute__((ext_vector_type(2))) __bf16 bf16x2;
__device__ __forceinline__ float dot2acc(u32 a, u32 b, float c){
  return __builtin_amdgcn_fdot2_f32_bf16(__builtin_bit_cast(bf16x2, a),
                                         __builtin_bit_cast(bf16x2, b), c, false);
}
#else
__device__ __forceinline__ float dot2acc(u32 a, u32 b, float c){
  float r = c;
  r += __uint_as_float(a << 16)          * __uint_as_float(b << 16);
  r += __uint_as_float(a & 0xffff0000u)  * __uint_as_float(b & 0xffff0000u);
  return r;
}
#endif

__device__ __forceinline__ float fsig(float x){ return 1.f/(1.f + __expf(-x)); }
__device__ __forceinline__ float ftanh_(float x){ return 1.f - 2.f/(1.f + __expf(2.f*x)); }

// DPP wave64 sum: VALU-only butterfly (no LDS-pipe traffic, unlike __shfl_xor
// which lowers to ds_swizzle). quad_perm xor1, xor2; row_ror:4, :8 -> row sums
// in all lanes; row_bcast15 + row_bcast31 fold rows; TOTAL valid in lane 63.
#define DPP_ADD(x, CTRL) \
  x += __int_as_float(__builtin_amdgcn_update_dpp(0, __float_as_int(x), CTRL, 0xF, 0xF, true))
#define DPP_REDUCE(x) { DPP_ADD(x, 0xB1); DPP_ADD(x, 0x4E); DPP_ADD(x, 0x124); \
                        DPP_ADD(x, 0x128); DPP_ADD(x, 0x142); DPP_ADD(x, 0x143); }

// ---------------- fp32 -> bf16 conversion (vectorized) ----------------
__global__ void conv_bf16(const float* __restrict__ src, u16* __restrict__ dst, int n4){
  int i = blockIdx.x * blockDim.x + threadIdx.x;
  if (i < n4){
    float4 v = reinterpret_cast<const float4*>(src)[i];
    ushort4 o;
    o.x = f2bf(v.x); o.y = f2bf(v.y); o.z = f2bf(v.z); o.w = f2bf(v.w);
    reinterpret_cast<ushort4*>(dst)[i] = o;
  }
}

// ---------------- x_proj GEMM: out[m][j][g] = sum_k A[m][k]*B[g*2048+j][k] + bias ----------------
__global__ __launch_bounds__(256) void gemm_xproj(
    const u16* __restrict__ A, const u16* __restrict__ B,
    const float* __restrict__ b_ih, const float* __restrict__ b_hh,
    u16* __restrict__ C)
{
  __shared__ __align__(16) u16 As[64][40];
  __shared__ __align__(16) u16 Bs[64][40];
  const int tid  = threadIdx.x;
  const int lane = tid & 63, wid = tid >> 6;
  const int wr = wid >> 1, wc = wid & 1;
  const int m0 = blockIdx.y * 64, n0 = blockIdx.x * 64;
  const int srow = tid >> 2, sseg = (tid & 3) * 8;

  f32x4 acc[2][2] = {};
  for (int k0 = 0; k0 < EMBED; k0 += 32){
    *(short8*)&As[srow][sseg] = *(const short8*)&A[(size_t)(m0 + srow) * EMBED + k0 + sseg];
    *(short8*)&Bs[srow][sseg] = *(const short8*)&B[(size_t)(n0 + srow) * EMBED + k0 + sseg];
    __syncthreads();
    const int rr = lane & 15, kg = (lane >> 4) * 8;
    #pragma unroll
    for (int mi = 0; mi < 2; ++mi){
      short8 a = *(const short8*)&As[wr*32 + mi*16 + rr][kg];
      #pragma unroll
      for (int ni = 0; ni < 2; ++ni){
        short8 b = *(const short8*)&Bs[wc*32 + ni*16 + rr][kg];
        acc[mi][ni] = __builtin_amdgcn_mfma_f32_16x16x32_bf16(a, b, acc[mi][ni], 0, 0, 0);
      }
    }
    __syncthreads();
  }
  const int rr = lane & 15, rg = (lane >> 4) * 4;
  #pragma unroll
  for (int ni = 0; ni < 2; ++ni){
    int n = n0 + wc*32 + ni*16 + rr;      // n = gate*2048 + j
    int g = n >> 11, j = n & 2047;
    float bias = b_ih[n] + b_hh[n];
    #pragma unroll
    for (int mi = 0; mi < 2; ++mi){
      #pragma unroll
      for (int r = 0; r < 4; ++r){
        int m = m0 + wr*32 + mi*16 + rg + r;
        C[(size_t)m * G4 + j*4 + g] = f2bf(acc[mi][ni][r] + bias);
      }
    }
  }
}

// ---------------- persistent LSTM scan (LDS weights + DPP reduce) ----------------
// 256 WGs x 512 threads, 1 WG/CU (132 KB dynamic LDS). Wave w of WG wg owns
// hidden unit j = wg*8 + w (gate rows g*2048+j). W_hh slice staged ONCE into
// LDS as packed bf16 pairs (128 KB). Per step, per lane: 16 weight
// ds_read_b128 + 4 h ds_read_b128 (both conflict-free, measured 0 conflicts
// R2-R5); reduction is DPP (VALU pipe) -- R5's shfl reduction put ~190 extra
// wave-ops/step on the LDS pipe and serialized after the barrier.
// h broadcast: htag[2][2048] words (tag<<16 | bf16(h)), relaxed agent-scope
// atomics (REQUIRED: plain loads may spin on stale non-coherent per-XCD L2),
// double-buffered by parity; tag+data in one word -> no fences.
__global__ __launch_bounds__(512) void lstm_scan(
    const float* __restrict__ Whh,   // [8192][2048] fp32
    const u16*  __restrict__ xp,     // [4096][2048][4] bf16 (packed by gemm)
    u32* htag)                       // [2][2048]
{
  extern __shared__ __align__(16) u32 smem[];      // 32768 u32 wlds + 1024 u32 h_bf
  u32* wlds = smem;
  u16* h_bf = (u16*)(smem + 32768);                // [4][512]: h_bf[r*512+i] = h[r*512+i]

  const int wg = blockIdx.x;
  const int tid = threadIdx.x;
  const int w = tid >> 6, lane = tid & 63;
  const int jrow = wg*8 + w;

  // ---- one-time weight staging: fp32 global -> packed bf16 pairs in LDS ----
  #pragma unroll
  for (int g = 0; g < 4; ++g){
    const float* row = Whh + (size_t)(g*HIDDEN + jrow) * HIDDEN;
    u32* dst = wlds + (g*8 + w) * 1024;
    #pragma unroll
    for (int r = 0; r < 4; ++r){
      const float* s = row + r*512 + lane*8;
      float4 a = *(const float4*)(s);
      float4 b = *(const float4*)(s + 4);
      uint4 pk;
      pk.x = (u32)f2bf(a.x) | ((u32)f2bf(a.y) << 16);
      pk.y = (u32)f2bf(a.z) | ((u32)f2bf(a.w) << 16);
      pk.z = (u32)f2bf(b.x) | ((u32)f2bf(b.y) << 16);
      pk.w = (u32)f2bf(b.z) | ((u32)f2bf(b.w) << 16);
      *(uint4*)(dst + r*256 + lane*4) = pk;
    }
  }
  __syncthreads();

  float c_reg = 0.f;
  const u32* w0 = wlds + (0*8 + w) * 1024 + lane*4;
  const u32* w1 = wlds + (1*8 + w) * 1024 + lane*4;
  const u32* w2 = wlds + (2*8 + w) * 1024 + lane*4;
  const u32* w3 = wlds + (3*8 + w) * 1024 + lane*4;

  for (int t = 0; t < LENGTH; ++t){
    // in-step xp load by the publisher lane (overlaps the poll; its use is at
    // the end of the step). NOT software-pipelined: the t+1 prefetch was the
    // one loop change shared by exactly the two regressed rounds (R4, R5).
    ushort4 xv = {0,0,0,0};
    if (lane == 63) xv = *(const ushort4*)(xp + (size_t)t * G4 + jrow * 4);

    // acquire step-t h (tag == t), buffer t&1; 4 coalesced atomic dword loads
    u32* src = htag + ((t & 1) << 11);
    const u32 tt = (u32)t << 16;
    u32 v0, v1, v2, v3;
    for (;;){
      v0 = __hip_atomic_load(&src[tid       ], __ATOMIC_RELAXED, __HIP_MEMORY_SCOPE_AGENT);
      v1 = __hip_atomic_load(&src[tid +  512], __ATOMIC_RELAXED, __HIP_MEMORY_SCOPE_AGENT);
      v2 = __hip_atomic_load(&src[tid + 1024], __ATOMIC_RELAXED, __HIP_MEMORY_SCOPE_AGENT);
      v3 = __hip_atomic_load(&src[tid + 1536], __ATOMIC_RELAXED, __HIP_MEMORY_SCOPE_AGENT);
      if ((((v0 ^ tt) | (v1 ^ tt) | (v2 ^ tt) | (v3 ^ tt)) & 0xffff0000u) == 0u) break;
      __builtin_amdgcn_s_sleep(1);
    }
    h_bf[0*512 + tid] = (u16)v0;
    h_bf[1*512 + tid] = (u16)v1;
    h_bf[2*512 + tid] = (u16)v2;
    h_bf[3*512 + tid] = (u16)v3;
    __syncthreads();

    // h fragments: chunk r covers h[r*512 + lane*8 .. +7] (conflict-free b128)
    uint4 ha = *(const uint4*)&h_bf[0*512 + lane*8];
    uint4 hb = *(const uint4*)&h_bf[1*512 + lane*8];
    uint4 hc = *(const uint4*)&h_bf[2*512 + lane*8];
    uint4 hd = *(const uint4*)&h_bf[3*512 + lane*8];

    float a0 = 0.f, a1 = 0.f, a2 = 0.f, a3 = 0.f;
    #define GATE_DOT(acc, wp) { \
      uint4 qa = *(const uint4*)(wp);       \
      uint4 qb = *(const uint4*)(wp + 256); \
      uint4 qc = *(const uint4*)(wp + 512); \
      uint4 qd = *(const uint4*)(wp + 768); \
      acc = dot2acc(qa.x, ha.x, acc); acc = dot2acc(qa.y, ha.y, acc); \
      acc = dot2acc(qa.z, ha.z, acc); acc = dot2acc(qa.w, ha.w, acc); \
      acc = dot2acc(qb.x, hb.x, acc); acc = dot2acc(qb.y, hb.y, acc); \
      acc = dot2acc(qb.z, hb.z, acc); acc = dot2acc(qb.w, hb.w, acc); \
      acc = dot2acc(qc.x, hc.x, acc); acc = dot2acc(qc.y, hc.y, acc); \
      acc = dot2acc(qc.z, hc.z, acc); acc = dot2acc(qc.w, hc.w, acc); \
      acc = dot2acc(qd.x, hd.x, acc); acc = dot2acc(qd.y, hd.y, acc); \
      acc = dot2acc(qd.z, hd.z, acc); acc = dot2acc(qd.w, hd.w, acc); }
    GATE_DOT(a0, w0); GATE_DOT(a1, w1); GATE_DOT(a2, w2); GATE_DOT(a3, w3);
    #undef GATE_DOT

    // VALU-only wave64 reduction; totals valid in lane 63
    DPP_REDUCE(a0); DPP_REDUCE(a1); DPP_REDUCE(a2); DPP_REDUCE(a3);

    if (lane == 63){
      float gi = fsig (a0 + bf2f(xv.x));
      float gf = fsig (a1 + bf2f(xv.y));
      float gg = ftanh_(a2 + bf2f(xv.z));
      float go = fsig (a3 + bf2f(xv.w));
      c_reg = gf * c_reg + gi * gg;
      float h = go * ftanh_(c_reg);
      u32 word = ((u32)(t + 1) << 16) | (u32)f2bf(h);
      __hip_atomic_store(&htag[(((t + 1) & 1) << 11) + jrow], word,
                         __ATOMIC_RELAXED, __HIP_MEMORY_SCOPE_AGENT);
    }
    // single barrier per step: poll success for t+1 implies every wave
    // published t+1, which happens only after it finished reading step-t h_bf.
  }
}

// ---------------- final head: sigmoid(h . W_fc + b_fc) ----------------
__global__ __launch_bounds__(256) void head_k(const u32* __restrict__ htag,
                                              const float* __restrict__ Wfc,
                                              const float* __restrict__ bfc,
                                              float* __restrict__ out){
  __shared__ float red[256];
  int tid = threadIdx.x;
  float s = 0.f;
  #pragma unroll
  for (int k = 0; k < 8; ++k){
    int j = tid * 8 + k;
    s += bf2f((u16)(htag[j] & 0xffffu)) * Wfc[j];   // tag 4096 lives in buffer 0
  }
  red[tid] = s;
  __syncthreads();
  for (int k = 128; k > 0; k >>= 1){
    if (tid < k) red[tid] += red[tid + k];
    __syncthreads();
  }
  if (tid == 0) out[0] = 1.f / (1.f + __expf(-(red[0] + bfc[0])));
}

// ---------------- launch ----------------
extern "C" void kernel_launch(void* const* d_in, const int* in_sizes, int n_in,
                              void* d_out, int out_size, void* d_ws, size_t ws_size,
                              hipStream_t stream){
  const float* x   = (const float*)d_in[0];   // [1,4096,1024]
  const float* Wih = (const float*)d_in[1];   // [8192,1024]
  const float* Whh = (const float*)d_in[2];   // [8192,2048]
  const float* bih = (const float*)d_in[3];   // [8192]
  const float* bhh = (const float*)d_in[4];   // [8192]
  const float* Wfc = (const float*)d_in[5];   // [1,2048]
  const float* bfc = (const float*)d_in[6];   // [1]
  float* out = (float*)d_out;

  char* ws = (char*)d_ws;
  u16* xp     = (u16*)(ws);                    // 4096*8192*2 = 67108864
  u16* x_bf   = (u16*)(ws + 67108864);         // 8388608
  u16* wih_bf = (u16*)(ws + 75497472);         // 16777216
  u32* htag   = (u32*)(ws + 92274688);         // 2*2048*4 = 16384

  hipMemsetAsync(htag, 0, 2 * HIDDEN * sizeof(u32), stream);
  conv_bf16<<<(EMBED*LENGTH/4 + 255)/256, 256, 0, stream>>>(x, x_bf, EMBED*LENGTH/4);
  conv_bf16<<<(G4*EMBED/4 + 255)/256, 256, 0, stream>>>(Wih, wih_bf, G4*EMBED/4);
  dim3 gg(G4/64, LENGTH/64);
  gemm_xproj<<<gg, 256, 0, stream>>>(x_bf, wih_bf, bih, bhh, xp);
  size_t lds_bytes = 32768 * 4 + 4096;         // 128KB weights + 4KB h_bf
  lstm_scan<<<256, 512, lds_bytes, stream>>>(Whh, xp, htag);
  head_k<<<1, 256, 0, stream>>>(htag, Wfc, bfc, out);
}

// Round 7
// 10117.941 us; speedup vs baseline: 1.8876x; 1.2491x over previous
//
#include <hip/hip_runtime.h>
#include <hip/hip_bf16.h>

#define EMBED   1024
#define HIDDEN  2048
#define G4      8192   // 4*HIDDEN
#define LENGTH  4096

typedef unsigned int   u32;
typedef unsigned short u16;
typedef __attribute__((ext_vector_type(4))) float f32x4;
typedef __attribute__((ext_vector_type(8))) short short8;
typedef __attribute__((ext_vector_type(4))) u32   u32x4;

__device__ __forceinline__ u16 f2bf(float x){
  __hip_bfloat16 h = __float2bfloat16(x);   // RNE
  return __builtin_bit_cast(u16, h);
}
__device__ __forceinline__ float bf2f(u16 b){
  return __uint_as_float(((u32)b) << 16);
}

#if __has_builtin(__builtin_amdgcn_fdot2_f32_bf16)
typedef __attribute__((ext_vector_type(2))) __bf16 bf16x2;
__device__ __forceinline__ float dot2acc(u32 a, u32 b, float c){
  return __builtin_amdgcn_fdot2_f32_bf16(__builtin_bit_cast(bf16x2, a),
                                         __builtin_bit_cast(bf16x2, b), c, false);
}
#else
__device__ __forceinline__ float dot2acc(u32 a, u32 b, float c){
  float r = c;
  r += __uint_as_float(a << 16)          * __uint_as_float(b << 16);
  r += __uint_as_float(a & 0xffff0000u)  * __uint_as_float(b & 0xffff0000u);
  return r;
}
#endif

__device__ __forceinline__ float fsig(float x){ return 1.f/(1.f + __expf(-x)); }
__device__ __forceinline__ float ftanh_(float x){ return 1.f - 2.f/(1.f + __expf(2.f*x)); }

// DPP wave64 sum: VALU-only butterfly (no LDS-pipe traffic). Total in lane 63.
#define DPP_ADD(x, CTRL) \
  x += __int_as_float(__builtin_amdgcn_update_dpp(0, __float_as_int(x), CTRL, 0xF, 0xF, true))
#define DPP_REDUCE(x) { DPP_ADD(x, 0xB1); DPP_ADD(x, 0x4E); DPP_ADD(x, 0x124); \
                        DPP_ADD(x, 0x128); DPP_ADD(x, 0x142); DPP_ADD(x, 0x143); }

// ---------------- fp32 -> bf16 conversion (vectorized) ----------------
__global__ void conv_bf16(const float* __restrict__ src, u16* __restrict__ dst, int n4){
  int i = blockIdx.x * blockDim.x + threadIdx.x;
  if (i < n4){
    float4 v = reinterpret_cast<const float4*>(src)[i];
    ushort4 o;
    o.x = f2bf(v.x); o.y = f2bf(v.y); o.z = f2bf(v.z); o.w = f2bf(v.w);
    reinterpret_cast<ushort4*>(dst)[i] = o;
  }
}

// ---------------- x_proj GEMM: out[m][j][g] = sum_k A[m][k]*B[g*2048+j][k] + bias ----------------
__global__ __launch_bounds__(256) void gemm_xproj(
    const u16* __restrict__ A, const u16* __restrict__ B,
    const float* __restrict__ b_ih, const float* __restrict__ b_hh,
    u16* __restrict__ C)
{
  __shared__ __align__(16) u16 As[64][40];
  __shared__ __align__(16) u16 Bs[64][40];
  const int tid  = threadIdx.x;
  const int lane = tid & 63, wid = tid >> 6;
  const int wr = wid >> 1, wc = wid & 1;
  const int m0 = blockIdx.y * 64, n0 = blockIdx.x * 64;
  const int srow = tid >> 2, sseg = (tid & 3) * 8;

  f32x4 acc[2][2] = {};
  for (int k0 = 0; k0 < EMBED; k0 += 32){
    *(short8*)&As[srow][sseg] = *(const short8*)&A[(size_t)(m0 + srow) * EMBED + k0 + sseg];
    *(short8*)&Bs[srow][sseg] = *(const short8*)&B[(size_t)(n0 + srow) * EMBED + k0 + sseg];
    __syncthreads();
    const int rr = lane & 15, kg = (lane >> 4) * 8;
    #pragma unroll
    for (int mi = 0; mi < 2; ++mi){
      short8 a = *(const short8*)&As[wr*32 + mi*16 + rr][kg];
      #pragma unroll
      for (int ni = 0; ni < 2; ++ni){
        short8 b = *(const short8*)&Bs[wc*32 + ni*16 + rr][kg];
        acc[mi][ni] = __builtin_amdgcn_mfma_f32_16x16x32_bf16(a, b, acc[mi][ni], 0, 0, 0);
      }
    }
    __syncthreads();
  }
  const int rr = lane & 15, rg = (lane >> 4) * 4;
  #pragma unroll
  for (int ni = 0; ni < 2; ++ni){
    int n = n0 + wc*32 + ni*16 + rr;      // n = gate*2048 + j
    int g = n >> 11, j = n & 2047;
    float bias = b_ih[n] + b_hh[n];
    #pragma unroll
    for (int mi = 0; mi < 2; ++mi){
      #pragma unroll
      for (int r = 0; r < 4; ++r){
        int m = m0 + wr*32 + mi*16 + rg + r;
        C[(size_t)m * G4 + j*4 + g] = f2bf(acc[mi][ni][r] + bias);
      }
    }
  }
}

// ---------------- persistent LSTM scan (LDS weights, prefetch-before-poll) ----------------
// 256 WGs x 512 threads, 1 WG/CU (132 KB dynamic LDS -> 2 waves/EU, so the
// VGPR budget is 256/wave; ~100 live VGPRs should allocate without spill).
// Per step, the 16 weight ds_read_b128 depend only on the static LDS weight
// region, so they issue BEFORE the poll loop: the ~0.8us LDS-pipe burst
// (160 wave-insts/CU) drains while the wave polls on the vmem pipe, instead
// of serializing after the barrier (R6: 3.1us/step = sync + LDS + compute in
// series). asm "+v" on each named result pins it live and blocks sinking.
// Poll is double-buffered (2 load-sets in flight) to halve detection latency.
__global__ __launch_bounds__(512) void lstm_scan(
    const float* __restrict__ Whh,   // [8192][2048] fp32
    const u16*  __restrict__ xp,     // [4096][2048][4] bf16 (packed by gemm)
    u32* htag)                       // [2][2048]
{
  extern __shared__ __align__(16) u32 smem[];      // 32768 u32 wlds + 1024 u32 h_bf
  u32* wlds = smem;
  u16* h_bf = (u16*)(smem + 32768);                // h_bf[r*512+i] = h[r*512+i]

  const int wg = blockIdx.x;
  const int tid = threadIdx.x;
  const int w = tid >> 6, lane = tid & 63;
  const int jrow = wg*8 + w;

  // ---- one-time weight staging: fp32 global -> packed bf16 pairs in LDS ----
  #pragma unroll
  for (int g = 0; g < 4; ++g){
    const float* row = Whh + (size_t)(g*HIDDEN + jrow) * HIDDEN;
    u32* dst = wlds + (g*8 + w) * 1024;
    #pragma unroll
    for (int r = 0; r < 4; ++r){
      const float* s = row + r*512 + lane*8;
      float4 a = *(const float4*)(s);
      float4 b = *(const float4*)(s + 4);
      uint4 pk;
      pk.x = (u32)f2bf(a.x) | ((u32)f2bf(a.y) << 16);
      pk.y = (u32)f2bf(a.z) | ((u32)f2bf(a.w) << 16);
      pk.z = (u32)f2bf(b.x) | ((u32)f2bf(b.y) << 16);
      pk.w = (u32)f2bf(b.z) | ((u32)f2bf(b.w) << 16);
      *(uint4*)(dst + r*256 + lane*4) = pk;
    }
  }
  __syncthreads();

  float c_reg = 0.f;
  const u32* w0 = wlds + (0*8 + w) * 1024 + lane*4;
  const u32* w1 = wlds + (1*8 + w) * 1024 + lane*4;
  const u32* w2 = wlds + (2*8 + w) * 1024 + lane*4;
  const u32* w3 = wlds + (3*8 + w) * 1024 + lane*4;

  for (int t = 0; t < LENGTH; ++t){
    // xp load (vmem; result needed only at step end)
    ushort4 xv = {0,0,0,0};
    if (lane == 63) xv = *(const ushort4*)(xp + (size_t)t * G4 + jrow * 4);

    // ---- weight prefetch: 16 ds_read_b128 issued BEFORE the poll ----
    u32x4 qa0 = *(const u32x4*)(w0);       u32x4 qb0 = *(const u32x4*)(w0 + 256);
    u32x4 qc0 = *(const u32x4*)(w0 + 512); u32x4 qd0 = *(const u32x4*)(w0 + 768);
    u32x4 qa1 = *(const u32x4*)(w1);       u32x4 qb1 = *(const u32x4*)(w1 + 256);
    u32x4 qc1 = *(const u32x4*)(w1 + 512); u32x4 qd1 = *(const u32x4*)(w1 + 768);
    u32x4 qa2 = *(const u32x4*)(w2);       u32x4 qb2 = *(const u32x4*)(w2 + 256);
    u32x4 qc2 = *(const u32x4*)(w2 + 512); u32x4 qd2 = *(const u32x4*)(w2 + 768);
    u32x4 qa3 = *(const u32x4*)(w3);       u32x4 qb3 = *(const u32x4*)(w3 + 256);
    u32x4 qc3 = *(const u32x4*)(w3 + 512); u32x4 qd3 = *(const u32x4*)(w3 + 768);
    #define OPQ4(v) asm volatile("" : "+v"(v))
    OPQ4(qa0); OPQ4(qb0); OPQ4(qc0); OPQ4(qd0);
    OPQ4(qa1); OPQ4(qb1); OPQ4(qc1); OPQ4(qd1);
    OPQ4(qa2); OPQ4(qb2); OPQ4(qc2); OPQ4(qd2);
    OPQ4(qa3); OPQ4(qb3); OPQ4(qc3); OPQ4(qd3);
    #undef OPQ4

    // ---- acquire step-t h (tag == t): double-buffered coalesced poll ----
    u32* src = htag + ((t & 1) << 11);
    const u32 tt = (u32)t << 16;
    u32 v0, v1, v2, v3;
    {
      u32 a0,a1,a2,a3, b0,b1,b2,b3;
      #define LOADSET(x0,x1,x2,x3) \
        x0 = __hip_atomic_load(&src[tid       ], __ATOMIC_RELAXED, __HIP_MEMORY_SCOPE_AGENT); \
        x1 = __hip_atomic_load(&src[tid +  512], __ATOMIC_RELAXED, __HIP_MEMORY_SCOPE_AGENT); \
        x2 = __hip_atomic_load(&src[tid + 1024], __ATOMIC_RELAXED, __HIP_MEMORY_SCOPE_AGENT); \
        x3 = __hip_atomic_load(&src[tid + 1536], __ATOMIC_RELAXED, __HIP_MEMORY_SCOPE_AGENT)
      #define CHK(x0,x1,x2,x3) \
        ((((x0 ^ tt) | (x1 ^ tt) | (x2 ^ tt) | (x3 ^ tt)) & 0xffff0000u) == 0u)
      LOADSET(a0,a1,a2,a3);
      for (;;){
        LOADSET(b0,b1,b2,b3);
        if (CHK(a0,a1,a2,a3)){ v0=a0; v1=a1; v2=a2; v3=a3; break; }
        LOADSET(a0,a1,a2,a3);
        if (CHK(b0,b1,b2,b3)){ v0=b0; v1=b1; v2=b2; v3=b3; break; }
      }
      #undef LOADSET
      #undef CHK
    }
    h_bf[0*512 + tid] = (u16)v0;
    h_bf[1*512 + tid] = (u16)v1;
    h_bf[2*512 + tid] = (u16)v2;
    h_bf[3*512 + tid] = (u16)v3;
    __syncthreads();

    // h fragments: chunk r covers h[r*512 + lane*8 .. +7] (conflict-free b128)
    u32x4 ha = *(const u32x4*)&h_bf[0*512 + lane*8];
    u32x4 hb = *(const u32x4*)&h_bf[1*512 + lane*8];
    u32x4 hc = *(const u32x4*)&h_bf[2*512 + lane*8];
    u32x4 hd = *(const u32x4*)&h_bf[3*512 + lane*8];

    float a0 = 0.f, a1 = 0.f, a2 = 0.f, a3 = 0.f;
    #define GATE_DOT(acc, qa,qb,qc,qd) { \
      acc = dot2acc(qa[0], ha[0], acc); acc = dot2acc(qa[1], ha[1], acc); \
      acc = dot2acc(qa[2], ha[2], acc); acc = dot2acc(qa[3], ha[3], acc); \
      acc = dot2acc(qb[0], hb[0], acc); acc = dot2acc(qb[1], hb[1], acc); \
      acc = dot2acc(qb[2], hb[2], acc); acc = dot2acc(qb[3], hb[3], acc); \
      acc = dot2acc(qc[0], hc[0], acc); acc = dot2acc(qc[1], hc[1], acc); \
      acc = dot2acc(qc[2], hc[2], acc); acc = dot2acc(qc[3], hc[3], acc); \
      acc = dot2acc(qd[0], hd[0], acc); acc = dot2acc(qd[1], hd[1], acc); \
      acc = dot2acc(qd[2], hd[2], acc); acc = dot2acc(qd[3], hd[3], acc); }
    GATE_DOT(a0, qa0,qb0,qc0,qd0);
    GATE_DOT(a1, qa1,qb1,qc1,qd1);
    GATE_DOT(a2, qa2,qb2,qc2,qd2);
    GATE_DOT(a3, qa3,qb3,qc3,qd3);
    #undef GATE_DOT

    // VALU-only wave64 reduction; totals valid in lane 63
    DPP_REDUCE(a0); DPP_REDUCE(a1); DPP_REDUCE(a2); DPP_REDUCE(a3);

    if (lane == 63){
      float gi = fsig (a0 + bf2f(xv.x));
      float gf = fsig (a1 + bf2f(xv.y));
      float gg = ftanh_(a2 + bf2f(xv.z));
      float go = fsig (a3 + bf2f(xv.w));
      c_reg = gf * c_reg + gi * gg;
      float h = go * ftanh_(c_reg);
      u32 word = ((u32)(t + 1) << 16) | (u32)f2bf(h);
      __hip_atomic_store(&htag[(((t + 1) & 1) << 11) + jrow], word,
                         __ATOMIC_RELAXED, __HIP_MEMORY_SCOPE_AGENT);
    }
    // single barrier per step: poll success for t+1 implies every wave
    // published t+1, which happens only after it finished reading step-t h_bf.
  }
}

// ---------------- final head: sigmoid(h . W_fc + b_fc) ----------------
__global__ __launch_bounds__(256) void head_k(const u32* __restrict__ htag,
                                              const float* __restrict__ Wfc,
                                              const float* __restrict__ bfc,
                                              float* __restrict__ out){
  __shared__ float red[256];
  int tid = threadIdx.x;
  float s = 0.f;
  #pragma unroll
  for (int k = 0; k < 8; ++k){
    int j = tid * 8 + k;
    s += bf2f((u16)(htag[j] & 0xffffu)) * Wfc[j];   // tag 4096 lives in buffer 0
  }
  red[tid] = s;
  __syncthreads();
  for (int k = 128; k > 0; k >>= 1){
    if (tid < k) red[tid] += red[tid + k];
    __syncthreads();
  }
  if (tid == 0) out[0] = 1.f / (1.f + __expf(-(red[0] + bfc[0])));
}

// ---------------- launch ----------------
extern "C" void kernel_launch(void* const* d_in, const int* in_sizes, int n_in,
                              void* d_out, int out_size, void* d_ws, size_t ws_size,
                              hipStream_t stream){
  const float* x   = (const float*)d_in[0];   // [1,4096,1024]
  const float* Wih = (const float*)d_in[1];   // [8192,1024]
  const float* Whh = (const float*)d_in[2];   // [8192,2048]
  const float* bih = (const float*)d_in[3];   // [8192]
  const float* bhh = (const float*)d_in[4];   // [8192]
  const float* Wfc = (const float*)d_in[5];   // [1,2048]
  const float* bfc = (const float*)d_in[6];   // [1]
  float* out = (float*)d_out;

  char* ws = (char*)d_ws;
  u16* xp     = (u16*)(ws);                    // 4096*8192*2 = 67108864
  u16* x_bf   = (u16*)(ws + 67108864);         // 8388608
  u16* wih_bf = (u16*)(ws + 75497472);         // 16777216
  u32* htag   = (u32*)(ws + 92274688);         // 2*2048*4 = 16384

  hipMemsetAsync(htag, 0, 2 * HIDDEN * sizeof(u32), stream);
  conv_bf16<<<(EMBED*LENGTH/4 + 255)/256, 256, 0, stream>>>(x, x_bf, EMBED*LENGTH/4);
  conv_bf16<<<(G4*EMBED/4 + 255)/256, 256, 0, stream>>>(Wih, wih_bf, G4*EMBED/4);
  dim3 gg(G4/64, LENGTH/64);
  gemm_xproj<<<gg, 256, 0, stream>>>(x_bf, wih_bf, bih, bhh, xp);
  size_t lds_bytes = 32768 * 4 + 4096;         // 128KB weights + 4KB h_bf
  lstm_scan<<<256, 512, lds_bytes, stream>>>(Whh, xp, htag);
  head_k<<<1, 256, 0, stream>>>(htag, Wfc, bfc, out);
}